// Round 4
// baseline (614.686 us; speedup 1.0000x reference)
//
#include <hip/hip_runtime.h>
#include <hip/hip_bf16.h>

typedef __bf16 bf16x8 __attribute__((ext_vector_type(8)));
typedef float f32x4 __attribute__((ext_vector_type(4)));
typedef float f32x16 __attribute__((ext_vector_type(16)));
typedef int int4v __attribute__((ext_vector_type(4)));
typedef unsigned int uint4v __attribute__((ext_vector_type(4)));
typedef unsigned short u16x8 __attribute__((ext_vector_type(8)));

#define N_NODES 8192
#define D_FEAT 128

// DIAGNOSTIC ROUND: identical compute path to round 2 (175.5 us best),
// except K2 (layer-1 GEMM, idempotent) is launched 17x to measure T_gemm
// from the total: T_gemm = (dur - 175.5) / 16.

// ---------------------------------------------------------------------------
// Bit->bf16 pair unpack: byte (8 adjacency bits) -> bf16x8 of {0.0, 1.0}.
__device__ __forceinline__ bf16x8 unpack_byte(unsigned dword, int sh) {
  unsigned P = ((dword >> sh) & 0xFFu) * 0x8001u;
  uint4v c;
  c[0] = (P & 0x10001u) * 0x3F80u;
  c[1] = ((P >> 2) & 0x10001u) * 0x3F80u;
  c[2] = ((P >> 4) & 0x10001u) * 0x3F80u;
  c[3] = ((P >> 6) & 0x10001u) * 0x3F80u;
  return __builtin_bit_cast(bf16x8, c);
}

// ---------------------------------------------------------------------------
// Bpk fragment build (verified round-2). Fragment f = kk*256 + ng*64 + l
// holds, at element e: F[sigma(kk*16 + (l>>5)*8 + e)][ng*32 + (l&31)],
// sigma(p) = 256*(p>>8) + 32*((p>>3)&7) + 4*(p&7) + ((p>>6)&3)
__device__ __forceinline__ void bpk32_store(const float* __restrict__ src,
                                            unsigned short* __restrict__ Bpk,
                                            int W) {
  const int kk = W >> 8;
  const int ng = (W >> 6) & 3;
  const int l = W & 63;
  const int d = ng * 32 + (l & 31);
  const int p0 = kk * 16 + (l >> 5) * 8;
  const int n0 = (p0 >> 8) * 256 + ((p0 >> 3) & 7) * 32 + ((p0 >> 6) & 3);
  u16x8 pk;
#pragma unroll
  for (int e = 0; e < 8; ++e) {
    __bf16 v = (__bf16)src[(long)(n0 + 4 * e) * D_FEAT + d];
    pk[e] = __builtin_bit_cast(unsigned short, v);
  }
  *(u16x8*)(Bpk + (long)W * 8) = pk;
}

// ---------------------------------------------------------------------------
// K1: mega-pack (round-2 form). Packs BOTH layers' adjacency rows into
// bits64 + deg via coalesced int4 loads + ballots; first 512 blocks build
// layer-1 Bpk.
__global__ __launch_bounds__(256) void pack_all_kernel(
    const int* __restrict__ adj, unsigned long long* __restrict__ bits64,
    int* __restrict__ deg, const float* __restrict__ fsrc,
    unsigned short* __restrict__ Bpk) {
  const int bx = blockIdx.x;
  const int t = threadIdx.x;

  if (bx < 512) {  // layer-1 Bpk build
    bpk32_store(fsrc, Bpk, bx * 256 + t);
    return;
  }

  const int row = bx - 512;  // 0..16383 across both layers
  const int w = t >> 6;
  const int lane = t & 63;
  const int4v* p = (const int4v*)(adj + ((long)row << 13));
  int4v v[8];
#pragma unroll
  for (int j = 0; j < 8; ++j) v[j] = p[j * 256 + t];

  unsigned long long* brow = bits64 + ((long)row << 7);
  int cnt = 0;
#pragma unroll
  for (int j = 0; j < 8; ++j) {
    unsigned long long b0 = __ballot(v[j][0] != 0);
    unsigned long long b1 = __ballot(v[j][1] != 0);
    unsigned long long b2 = __ballot(v[j][2] != 0);
    unsigned long long b3 = __ballot(v[j][3] != 0);
    cnt += __popcll(b0) + __popcll(b1) + __popcll(b2) + __popcll(b3);
    unsigned long long bsel = b0;
    if (lane == 1) bsel = b1;
    if (lane == 2) bsel = b2;
    if (lane == 3) bsel = b3;
    if (lane < 4) brow[16 * j + 4 * w + lane] = bsel;
  }
  __shared__ int red[4];
  if (lane == 0) red[w] = cnt;
  __syncthreads();
  if (t == 0) deg[row] = red[0] + red[1] + red[2] + red[3];
}

// ---------------------------------------------------------------------------
// K3: rebuild Bpk from layer-1 output.
__global__ __launch_bounds__(256) void bpk_build32_kernel(
    const float* __restrict__ src, unsigned short* __restrict__ Bpk) {
  bpk32_store(src, Bpk, blockIdx.x * 256 + threadIdx.x);
}

// ---------------------------------------------------------------------------
// Layer body, 32x32x16 MFMA (round-2 form: 2 m-tiles/wave, split-K4).
// Block = 64 rows x 64 cols, 512 thr = 8 waves = 2 col-groups x 4 K-quarters.
// A layout: lane l holds row l&31, K-bits (l>>5)*8..+7 of each 16-bit K-step.
// C/D (m101): col=l&31, row=(r&3)+8*(r>>2)+4*(l>>5).
__device__ __forceinline__ void layer_body32(
    int rowblk, int nthalf,
    const unsigned* __restrict__ bits, const int* __restrict__ deg,
    const unsigned short* __restrict__ Bpk,
    const float* fin, float* fout,
    f32x4 (*red)[2][2][4][64]) {
  const int tid = threadIdx.x;
  const int lane = tid & 63;
  const int w = tid >> 6;        // 0..7
  const int ntl = w & 1;         // col group within block
  const int kh = w >> 1;         // 0..3  K-quarter (2048 bits)
  const int l31 = lane & 31;
  const int lh = lane >> 5;      // 0/1
  const int m0 = rowblk * 64;
  const int ng = nthalf * 2 + ntl;  // 0..3 global 32-col group
  const int shA = lh * 8;
  const int shB = shA + 16;

  // A: row stride 1 KiB (256 u32); K-quarter = 16 uint4.
  const uint4v* ap0 = (const uint4v*)(bits + ((long)(m0 + l31) << 8)) + kh * 16;
  const uint4v* ap1 =
      (const uint4v*)(bits + ((long)(m0 + 32 + l31) << 8)) + kh * 16;
  // B: fragment f = kk*256 + ng*64 + lane; kk = kh*128 + kg*8 + s.
  const bf16x8* bp = (const bf16x8*)Bpk + ((long)kh << 15) + ng * 64 + lane;

  f32x16 acc0 = {0.f, 0.f, 0.f, 0.f, 0.f, 0.f, 0.f, 0.f,
                 0.f, 0.f, 0.f, 0.f, 0.f, 0.f, 0.f, 0.f};
  f32x16 acc1 = {0.f, 0.f, 0.f, 0.f, 0.f, 0.f, 0.f, 0.f,
                 0.f, 0.f, 0.f, 0.f, 0.f, 0.f, 0.f, 0.f};

#pragma unroll 2
  for (int kg = 0; kg < 16; ++kg) {
    uint4v a0 = ap0[kg];
    uint4v a1 = ap1[kg];
#pragma unroll
    for (int s = 0; s < 8; ++s) {
      bf16x8 bv = *bp;
      bp += 256;
      const int sh = (s & 1) ? shB : shA;
      acc0 = __builtin_amdgcn_mfma_f32_32x32x16_bf16(
          unpack_byte(a0[s >> 1], sh), bv, acc0, 0, 0, 0);
      acc1 = __builtin_amdgcn_mfma_f32_32x32x16_bf16(
          unpack_byte(a1[s >> 1], sh), bv, acc1, 0, 0, 0);
    }
  }

  // Split-K combine: quarters 1..3 store, quarter 0 accumulates.
  if (kh) {
#define STORE_CHUNK(c)                                                       \
  red[kh - 1][ntl][0][c][lane] = __builtin_shufflevector(                    \
      acc0, acc0, 4 * (c), 4 * (c) + 1, 4 * (c) + 2, 4 * (c) + 3);           \
  red[kh - 1][ntl][1][c][lane] = __builtin_shufflevector(                    \
      acc1, acc1, 4 * (c), 4 * (c) + 1, 4 * (c) + 2, 4 * (c) + 3);
    STORE_CHUNK(0)
    STORE_CHUNK(1)
    STORE_CHUNK(2)
    STORE_CHUNK(3)
#undef STORE_CHUNK
  }
  __syncthreads();
  if (kh) return;

#pragma unroll
  for (int q = 0; q < 3; ++q) {
#pragma unroll
    for (int c = 0; c < 4; ++c) {
      f32x4 r0 = red[q][ntl][0][c][lane];
      f32x4 r1 = red[q][ntl][1][c][lane];
#pragma unroll
      for (int k = 0; k < 4; ++k) {
        acc0[4 * c + k] += r0[k];
        acc1[4 * c + k] += r1[k];
      }
    }
  }

  // Epilogue: col = ng*32 + l31, row = m0 + mt*32 + (r&3) + 8*(r>>2) + 4*lh.
#pragma unroll
  for (int mt = 0; mt < 2; ++mt) {
#pragma unroll
    for (int r = 0; r < 16; ++r) {
      const int row = m0 + mt * 32 + (r & 3) + 8 * (r >> 2) + 4 * lh;
      const int dg = deg[row];
      const float a = mt ? acc1[r] : acc0[r];
      const long off = (long)row * D_FEAT + ng * 32 + l31;
      fout[off] = dg > 0 ? a * (1.0f / (float)dg) : fin[off];
    }
  }
}

// ---------------------------------------------------------------------------
// K2/K4: standalone layer GEMM. grid 256 = 128 rowblks x 2 col-halves.
__global__ __launch_bounds__(512, 2) void layer32_kernel(
    const unsigned* __restrict__ bits, const int* __restrict__ deg,
    const unsigned short* __restrict__ Bpk, const float* fin, float* fout) {
  __shared__ __align__(16) f32x4 red[3][2][2][4][64];  // 48 KiB
  layer_body32(blockIdx.x >> 1, blockIdx.x & 1, bits, deg, Bpk, fin, fout,
               red);
}

// ---------------------------------------------------------------------------
// Fallback path (round-1 verified), used only if ws too small.
__global__ __launch_bounds__(256) void transpose_cast_kernel(
    const float* __restrict__ src, unsigned short* __restrict__ dst) {
  __shared__ float tile[64][129];
  const int t = threadIdx.x;
  const int nbase = blockIdx.x * 64;
#pragma unroll
  for (int i = 0; i < 32; ++i) {
    int idx = t + i * 256;
    int nl = idx >> 7;
    int d = idx & 127;
    tile[nl][d] = src[(long)(nbase + nl) * D_FEAT + d];
  }
  __syncthreads();
#pragma unroll
  for (int i = 0; i < 32; ++i) {
    int idx = t + i * 256;
    int d = idx >> 6;
    int nl = idx & 63;
    __bf16 b = (__bf16)tile[nl][d];
    dst[(long)d * N_NODES + nbase + nl] = __builtin_bit_cast(unsigned short, b);
  }
}

__global__ __launch_bounds__(512) void layer_kernel_direct(
    const int* __restrict__ adj, const unsigned short* __restrict__ BT,
    const float* __restrict__ fin, float* __restrict__ fout) {
  const int tid = threadIdx.x;
  const int lane = tid & 63;
  const int w = tid >> 6;
  const int m0 = blockIdx.x * 32 + (w >> 2) * 16;
  const int n0 = (w & 3) * 32;
  const int lr = lane & 15;
  const int kc = lane >> 4;

  const int4v* ap = (const int4v*)(adj + (long)(m0 + lr) * N_NODES + kc * 8);
  const bf16x8* bp0 = (const bf16x8*)(BT + (long)(n0 + lr) * N_NODES + kc * 8);
  const bf16x8* bp1 =
      (const bf16x8*)(BT + (long)(n0 + 16 + lr) * N_NODES + kc * 8);

  f32x4 acc0 = {0.f, 0.f, 0.f, 0.f};
  f32x4 acc1 = {0.f, 0.f, 0.f, 0.f};
  int degv = 0;

#pragma unroll 4
  for (int k = 0; k < N_NODES; k += 32) {
    int4v alo = ap[0];
    int4v ahi = ap[1];
    bf16x8 b0 = bp0[0];
    bf16x8 b1 = bp1[0];
    ap += 8;
    bp0 += 4;
    bp1 += 4;
    unsigned short u[8];
    u[0] = alo[0] ? 0x3F80 : 0;
    u[1] = alo[1] ? 0x3F80 : 0;
    u[2] = alo[2] ? 0x3F80 : 0;
    u[3] = alo[3] ? 0x3F80 : 0;
    u[4] = ahi[0] ? 0x3F80 : 0;
    u[5] = ahi[1] ? 0x3F80 : 0;
    u[6] = ahi[2] ? 0x3F80 : 0;
    u[7] = ahi[3] ? 0x3F80 : 0;
    degv += alo[0] + alo[1] + alo[2] + alo[3] + ahi[0] + ahi[1] + ahi[2] +
            ahi[3];
    bf16x8 a;
    memcpy(&a, u, 16);
    acc0 = __builtin_amdgcn_mfma_f32_16x16x32_bf16(a, b0, acc0, 0, 0, 0);
    acc1 = __builtin_amdgcn_mfma_f32_16x16x32_bf16(a, b1, acc1, 0, 0, 0);
  }

  degv += __shfl_xor(degv, 16);
  degv += __shfl_xor(degv, 32);
  int dgv[4];
#pragma unroll
  for (int j = 0; j < 4; ++j) dgv[j] = __shfl(degv, kc * 4 + j);

#pragma unroll
  for (int t = 0; t < 2; ++t) {
    const f32x4 acc = t ? acc1 : acc0;
    const int col = n0 + t * 16 + lr;
#pragma unroll
    for (int j = 0; j < 4; ++j) {
      const long off = (long)(m0 + kc * 4 + j) * D_FEAT + col;
      fout[off] = dgv[j] > 0 ? acc[j] * (1.0f / (float)dgv[j]) : fin[off];
    }
  }
}

// ---------------------------------------------------------------------------
extern "C" void kernel_launch(void* const* d_in, const int* in_sizes, int n_in,
                              void* d_out, int out_size, void* d_ws,
                              size_t ws_size, hipStream_t stream) {
  const float* features = (const float*)d_in[0];
  const int* adj = (const int*)d_in[1];
  float* out = (float*)d_out;
  const long NN = (long)N_NODES * N_NODES;

  const size_t BITS_BYTES = 2ul * N_NODES * 128 * 8;      // 16 MiB
  const size_t BPK_BYTES = (size_t)D_FEAT * N_NODES * 2;  // 2 MiB
  const size_t NEED = BITS_BYTES + 65536 + BPK_BYTES;

  if (ws_size >= NEED) {
    unsigned long long* bits64 = (unsigned long long*)d_ws;
    int* degw = (int*)((char*)d_ws + BITS_BYTES);
    unsigned short* Bpk = (unsigned short*)((char*)d_ws + BITS_BYTES + 65536);
    const unsigned* bits32 = (const unsigned*)d_ws;

    // K1: pack both layers' adjacency + build layer-1 Bpk.
    pack_all_kernel<<<2 * N_NODES + 512, 256, 0, stream>>>(adj, bits64, degw,
                                                           features, Bpk);
    // K2: layer-1 GEMM, launched 17x (idempotent) — amplification probe:
    // T_gemm = (dur_us - 175.5) / 16.
    for (int rep = 0; rep < 17; ++rep) {
      layer32_kernel<<<256, 512, 0, stream>>>(bits32, degw, Bpk, features,
                                              out);
    }
    // K3: rebuild Bpk from layer-1 output.
    bpk_build32_kernel<<<512, 256, 0, stream>>>(out, Bpk);
    // K4: layer-2 GEMM.
    layer32_kernel<<<256, 512, 0, stream>>>(bits32 + (size_t)N_NODES * 256,
                                            degw + N_NODES, Bpk, out, out);
  } else {
    // Fallback: round-1 verified path (needs only 2 MiB ws)
    unsigned short* BTw = (unsigned short*)d_ws;
    transpose_cast_kernel<<<N_NODES / 64, 256, 0, stream>>>(features, BTw);
    layer_kernel_direct<<<N_NODES / 32, 512, 0, stream>>>(adj, BTw, features,
                                                          out);
    transpose_cast_kernel<<<N_NODES / 64, 256, 0, stream>>>(out, BTw);
    layer_kernel_direct<<<N_NODES / 32, 512, 0, stream>>>(adj + NN, BTw, out,
                                                          out);
  }
}

// Round 5
// 164.980 us; speedup vs baseline: 3.7258x; 3.7258x over previous
//
#include <hip/hip_runtime.h>
#include <hip/hip_bf16.h>

typedef __bf16 bf16x8 __attribute__((ext_vector_type(8)));
typedef float f32x4 __attribute__((ext_vector_type(4)));
typedef float f32x16 __attribute__((ext_vector_type(16)));
typedef int int4v __attribute__((ext_vector_type(4)));
typedef unsigned int uint4v __attribute__((ext_vector_type(4)));
typedef unsigned short u16x8 __attribute__((ext_vector_type(8)));

#define N_NODES 8192
#define D_FEAT 128

// Round-4 probe result: T_gemm = 27.5 us (258 cyc/s-step ~= L2 latency ->
// load->use serialization). This round: distance-1 ping-pong register
// prefetch of B fragments + A dwords in the GEMM K-loop. Everything else
// identical to the 175.5-us round-2 configuration.

// ---------------------------------------------------------------------------
// Bit->bf16 pair unpack: byte (8 adjacency bits) -> bf16x8 of {0.0, 1.0}.
__device__ __forceinline__ bf16x8 unpack_byte(unsigned dword, int sh) {
  unsigned P = ((dword >> sh) & 0xFFu) * 0x8001u;
  uint4v c;
  c[0] = (P & 0x10001u) * 0x3F80u;
  c[1] = ((P >> 2) & 0x10001u) * 0x3F80u;
  c[2] = ((P >> 4) & 0x10001u) * 0x3F80u;
  c[3] = ((P >> 6) & 0x10001u) * 0x3F80u;
  return __builtin_bit_cast(bf16x8, c);
}

// ---------------------------------------------------------------------------
// Bpk fragment build (verified round-2). Fragment f = kk*256 + ng*64 + l
// holds, at element e: F[sigma(kk*16 + (l>>5)*8 + e)][ng*32 + (l&31)],
// sigma(p) = 256*(p>>8) + 32*((p>>3)&7) + 4*(p&7) + ((p>>6)&3)
__device__ __forceinline__ void bpk32_store(const float* __restrict__ src,
                                            unsigned short* __restrict__ Bpk,
                                            int W) {
  const int kk = W >> 8;
  const int ng = (W >> 6) & 3;
  const int l = W & 63;
  const int d = ng * 32 + (l & 31);
  const int p0 = kk * 16 + (l >> 5) * 8;
  const int n0 = (p0 >> 8) * 256 + ((p0 >> 3) & 7) * 32 + ((p0 >> 6) & 3);
  u16x8 pk;
#pragma unroll
  for (int e = 0; e < 8; ++e) {
    __bf16 v = (__bf16)src[(long)(n0 + 4 * e) * D_FEAT + d];
    pk[e] = __builtin_bit_cast(unsigned short, v);
  }
  *(u16x8*)(Bpk + (long)W * 8) = pk;
}

// ---------------------------------------------------------------------------
// K1: mega-pack (round-2 form). Packs BOTH layers' adjacency rows into
// bits64 + deg via coalesced int4 loads + ballots; first 512 blocks build
// layer-1 Bpk.
__global__ __launch_bounds__(256) void pack_all_kernel(
    const int* __restrict__ adj, unsigned long long* __restrict__ bits64,
    int* __restrict__ deg, const float* __restrict__ fsrc,
    unsigned short* __restrict__ Bpk) {
  const int bx = blockIdx.x;
  const int t = threadIdx.x;

  if (bx < 512) {  // layer-1 Bpk build
    bpk32_store(fsrc, Bpk, bx * 256 + t);
    return;
  }

  const int row = bx - 512;  // 0..16383 across both layers
  const int w = t >> 6;
  const int lane = t & 63;
  const int4v* p = (const int4v*)(adj + ((long)row << 13));
  int4v v[8];
#pragma unroll
  for (int j = 0; j < 8; ++j) v[j] = p[j * 256 + t];

  unsigned long long* brow = bits64 + ((long)row << 7);
  int cnt = 0;
#pragma unroll
  for (int j = 0; j < 8; ++j) {
    unsigned long long b0 = __ballot(v[j][0] != 0);
    unsigned long long b1 = __ballot(v[j][1] != 0);
    unsigned long long b2 = __ballot(v[j][2] != 0);
    unsigned long long b3 = __ballot(v[j][3] != 0);
    cnt += __popcll(b0) + __popcll(b1) + __popcll(b2) + __popcll(b3);
    unsigned long long bsel = b0;
    if (lane == 1) bsel = b1;
    if (lane == 2) bsel = b2;
    if (lane == 3) bsel = b3;
    if (lane < 4) brow[16 * j + 4 * w + lane] = bsel;
  }
  __shared__ int red[4];
  if (lane == 0) red[w] = cnt;
  __syncthreads();
  if (t == 0) deg[row] = red[0] + red[1] + red[2] + red[3];
}

// ---------------------------------------------------------------------------
// K3: rebuild Bpk from layer-1 output.
__global__ __launch_bounds__(256) void bpk_build32_kernel(
    const float* __restrict__ src, unsigned short* __restrict__ Bpk) {
  bpk32_store(src, Bpk, blockIdx.x * 256 + threadIdx.x);
}

// ---------------------------------------------------------------------------
// Layer body, 32x32x16 MFMA, split-K4, 2 m-tiles/wave (round-2 geometry),
// now with explicit distance-1 ping-pong prefetch in the K-loop.
// A layout: lane l holds row l&31, K-bits (l>>5)*8..+7 of each 16-bit K-step.
// C/D (m101): col=l&31, row=(r&3)+8*(r>>2)+4*(l>>5).
__device__ __forceinline__ void layer_body32(
    int rowblk, int nthalf,
    const unsigned* __restrict__ bits, const int* __restrict__ deg,
    const unsigned short* __restrict__ Bpk,
    const float* fin, float* fout,
    f32x4 (*red)[2][2][4][64]) {
  const int tid = threadIdx.x;
  const int lane = tid & 63;
  const int w = tid >> 6;        // 0..7
  const int ntl = w & 1;         // col group within block
  const int kh = w >> 1;         // 0..3  K-quarter (2048 bits)
  const int l31 = lane & 31;
  const int lh = lane >> 5;      // 0/1
  const int m0 = rowblk * 64;
  const int ng = nthalf * 2 + ntl;  // 0..3 global 32-col group
  const int shA = lh * 8;
  const int shB = shA + 16;

  // A: row stride 1 KiB (256 u32); K-quarter = 16 uint4.
  const uint4v* ap0 = (const uint4v*)(bits + ((long)(m0 + l31) << 8)) + kh * 16;
  const uint4v* ap1 =
      (const uint4v*)(bits + ((long)(m0 + 32 + l31) << 8)) + kh * 16;
  // B: fragment f = kk*256 + ng*64 + lane; kk = kh*128 + kg*8 + s.
  // Quarter base; per kg stride = 8 kk * 256 frag = 2048 frags.
  const bf16x8* bpq = (const bf16x8*)Bpk + ((long)kh << 15) + ng * 64 + lane;

  f32x16 acc0 = {0.f, 0.f, 0.f, 0.f, 0.f, 0.f, 0.f, 0.f,
                 0.f, 0.f, 0.f, 0.f, 0.f, 0.f, 0.f, 0.f};
  f32x16 acc1 = {0.f, 0.f, 0.f, 0.f, 0.f, 0.f, 0.f, 0.f,
                 0.f, 0.f, 0.f, 0.f, 0.f, 0.f, 0.f, 0.f};

#define COMPUTE_KG(A0, A1, BV)                                               \
  {                                                                          \
    _Pragma("unroll") for (int s = 0; s < 8; ++s) {                          \
      const int sh = (s & 1) ? shB : shA;                                    \
      acc0 = __builtin_amdgcn_mfma_f32_32x32x16_bf16(                        \
          unpack_byte((A0)[s >> 1], sh), (BV)[s], acc0, 0, 0, 0);            \
      acc1 = __builtin_amdgcn_mfma_f32_32x32x16_bf16(                        \
          unpack_byte((A1)[s >> 1], sh), (BV)[s], acc1, 0, 0, 0);            \
    }                                                                        \
  }

  // Prologue: load kg=0 into buffer A.
  uint4v a0c = ap0[0], a1c = ap1[0];
  bf16x8 bvA[8], bvB[8];
#pragma unroll
  for (int s = 0; s < 8; ++s) bvA[s] = bpq[s * 256];

#pragma unroll 1
  for (int kg = 0; kg < 16; kg += 2) {
    // Prefetch kg+1 into buffer B (kg+1 <= 15 always).
    uint4v a0n = ap0[kg + 1];
    uint4v a1n = ap1[kg + 1];
#pragma unroll
    for (int s = 0; s < 8; ++s) bvB[s] = bpq[(kg + 1) * 2048 + s * 256];
    COMPUTE_KG(a0c, a1c, bvA)  // kg (even)

    // Prefetch kg+2 into buffer A (clamped: last pair re-loads kg+1).
    const int kn = (kg + 2 < 16) ? kg + 2 : 15;
    a0c = ap0[kn];
    a1c = ap1[kn];
#pragma unroll
    for (int s = 0; s < 8; ++s) bvA[s] = bpq[kn * 2048 + s * 256];
    COMPUTE_KG(a0n, a1n, bvB)  // kg+1 (odd)
  }
#undef COMPUTE_KG

  // Split-K combine: quarters 1..3 store, quarter 0 accumulates.
  if (kh) {
#define STORE_CHUNK(c)                                                       \
  red[kh - 1][ntl][0][c][lane] = __builtin_shufflevector(                    \
      acc0, acc0, 4 * (c), 4 * (c) + 1, 4 * (c) + 2, 4 * (c) + 3);           \
  red[kh - 1][ntl][1][c][lane] = __builtin_shufflevector(                    \
      acc1, acc1, 4 * (c), 4 * (c) + 1, 4 * (c) + 2, 4 * (c) + 3);
    STORE_CHUNK(0)
    STORE_CHUNK(1)
    STORE_CHUNK(2)
    STORE_CHUNK(3)
#undef STORE_CHUNK
  }
  __syncthreads();
  if (kh) return;

#pragma unroll
  for (int q = 0; q < 3; ++q) {
#pragma unroll
    for (int c = 0; c < 4; ++c) {
      f32x4 r0 = red[q][ntl][0][c][lane];
      f32x4 r1 = red[q][ntl][1][c][lane];
#pragma unroll
      for (int k = 0; k < 4; ++k) {
        acc0[4 * c + k] += r0[k];
        acc1[4 * c + k] += r1[k];
      }
    }
  }

  // Epilogue: col = ng*32 + l31, row = m0 + mt*32 + (r&3) + 8*(r>>2) + 4*lh.
#pragma unroll
  for (int mt = 0; mt < 2; ++mt) {
#pragma unroll
    for (int r = 0; r < 16; ++r) {
      const int row = m0 + mt * 32 + (r & 3) + 8 * (r >> 2) + 4 * lh;
      const int dg = deg[row];
      const float a = mt ? acc1[r] : acc0[r];
      const long off = (long)row * D_FEAT + ng * 32 + l31;
      fout[off] = dg > 0 ? a * (1.0f / (float)dg) : fin[off];
    }
  }
}

// ---------------------------------------------------------------------------
// K2/K4: standalone layer GEMM. grid 256 = 128 rowblks x 2 col-halves.
__global__ __launch_bounds__(512, 2) void layer32_kernel(
    const unsigned* __restrict__ bits, const int* __restrict__ deg,
    const unsigned short* __restrict__ Bpk, const float* fin, float* fout) {
  __shared__ __align__(16) f32x4 red[3][2][2][4][64];  // 48 KiB
  layer_body32(blockIdx.x >> 1, blockIdx.x & 1, bits, deg, Bpk, fin, fout,
               red);
}

// ---------------------------------------------------------------------------
// Fallback path (round-1 verified), used only if ws too small.
__global__ __launch_bounds__(256) void transpose_cast_kernel(
    const float* __restrict__ src, unsigned short* __restrict__ dst) {
  __shared__ float tile[64][129];
  const int t = threadIdx.x;
  const int nbase = blockIdx.x * 64;
#pragma unroll
  for (int i = 0; i < 32; ++i) {
    int idx = t + i * 256;
    int nl = idx >> 7;
    int d = idx & 127;
    tile[nl][d] = src[(long)(nbase + nl) * D_FEAT + d];
  }
  __syncthreads();
#pragma unroll
  for (int i = 0; i < 32; ++i) {
    int idx = t + i * 256;
    int d = idx >> 6;
    int nl = idx & 63;
    __bf16 b = (__bf16)tile[nl][d];
    dst[(long)d * N_NODES + nbase + nl] = __builtin_bit_cast(unsigned short, b);
  }
}

__global__ __launch_bounds__(512) void layer_kernel_direct(
    const int* __restrict__ adj, const unsigned short* __restrict__ BT,
    const float* __restrict__ fin, float* __restrict__ fout) {
  const int tid = threadIdx.x;
  const int lane = tid & 63;
  const int w = tid >> 6;
  const int m0 = blockIdx.x * 32 + (w >> 2) * 16;
  const int n0 = (w & 3) * 32;
  const int lr = lane & 15;
  const int kc = lane >> 4;

  const int4v* ap = (const int4v*)(adj + (long)(m0 + lr) * N_NODES + kc * 8);
  const bf16x8* bp0 = (const bf16x8*)(BT + (long)(n0 + lr) * N_NODES + kc * 8);
  const bf16x8* bp1 =
      (const bf16x8*)(BT + (long)(n0 + 16 + lr) * N_NODES + kc * 8);

  f32x4 acc0 = {0.f, 0.f, 0.f, 0.f};
  f32x4 acc1 = {0.f, 0.f, 0.f, 0.f};
  int degv = 0;

#pragma unroll 4
  for (int k = 0; k < N_NODES; k += 32) {
    int4v alo = ap[0];
    int4v ahi = ap[1];
    bf16x8 b0 = bp0[0];
    bf16x8 b1 = bp1[0];
    ap += 8;
    bp0 += 4;
    bp1 += 4;
    unsigned short u[8];
    u[0] = alo[0] ? 0x3F80 : 0;
    u[1] = alo[1] ? 0x3F80 : 0;
    u[2] = alo[2] ? 0x3F80 : 0;
    u[3] = alo[3] ? 0x3F80 : 0;
    u[4] = ahi[0] ? 0x3F80 : 0;
    u[5] = ahi[1] ? 0x3F80 : 0;
    u[6] = ahi[2] ? 0x3F80 : 0;
    u[7] = ahi[3] ? 0x3F80 : 0;
    degv += alo[0] + alo[1] + alo[2] + alo[3] + ahi[0] + ahi[1] + ahi[2] +
            ahi[3];
    bf16x8 a;
    memcpy(&a, u, 16);
    acc0 = __builtin_amdgcn_mfma_f32_16x16x32_bf16(a, b0, acc0, 0, 0, 0);
    acc1 = __builtin_amdgcn_mfma_f32_16x16x32_bf16(a, b1, acc1, 0, 0, 0);
  }

  degv += __shfl_xor(degv, 16);
  degv += __shfl_xor(degv, 32);
  int dgv[4];
#pragma unroll
  for (int j = 0; j < 4; ++j) dgv[j] = __shfl(degv, kc * 4 + j);

#pragma unroll
  for (int t = 0; t < 2; ++t) {
    const f32x4 acc = t ? acc1 : acc0;
    const int col = n0 + t * 16 + lr;
#pragma unroll
    for (int j = 0; j < 4; ++j) {
      const long off = (long)(m0 + kc * 4 + j) * D_FEAT + col;
      fout[off] = dgv[j] > 0 ? acc[j] * (1.0f / (float)dgv[j]) : fin[off];
    }
  }
}

// ---------------------------------------------------------------------------
extern "C" void kernel_launch(void* const* d_in, const int* in_sizes, int n_in,
                              void* d_out, int out_size, void* d_ws,
                              size_t ws_size, hipStream_t stream) {
  const float* features = (const float*)d_in[0];
  const int* adj = (const int*)d_in[1];
  float* out = (float*)d_out;
  const long NN = (long)N_NODES * N_NODES;

  const size_t BITS_BYTES = 2ul * N_NODES * 128 * 8;      // 16 MiB
  const size_t BPK_BYTES = (size_t)D_FEAT * N_NODES * 2;  // 2 MiB
  const size_t NEED = BITS_BYTES + 65536 + BPK_BYTES;

  if (ws_size >= NEED) {
    unsigned long long* bits64 = (unsigned long long*)d_ws;
    int* degw = (int*)((char*)d_ws + BITS_BYTES);
    unsigned short* Bpk = (unsigned short*)((char*)d_ws + BITS_BYTES + 65536);
    const unsigned* bits32 = (const unsigned*)d_ws;

    // K1: pack both layers' adjacency + build layer-1 Bpk.
    pack_all_kernel<<<2 * N_NODES + 512, 256, 0, stream>>>(adj, bits64, degw,
                                                           features, Bpk);
    // K2: layer-1 GEMM (prefetched K-loop).
    layer32_kernel<<<256, 512, 0, stream>>>(bits32, degw, Bpk, features, out);
    // K3: rebuild Bpk from layer-1 output.
    bpk_build32_kernel<<<512, 256, 0, stream>>>(out, Bpk);
    // K4: layer-2 GEMM.
    layer32_kernel<<<256, 512, 0, stream>>>(bits32 + (size_t)N_NODES * 256,
                                            degw + N_NODES, Bpk, out, out);
  } else {
    // Fallback: round-1 verified path (needs only 2 MiB ws)
    unsigned short* BTw = (unsigned short*)d_ws;
    transpose_cast_kernel<<<N_NODES / 64, 256, 0, stream>>>(features, BTw);
    layer_kernel_direct<<<N_NODES / 32, 512, 0, stream>>>(adj, BTw, features,
                                                          out);
    transpose_cast_kernel<<<N_NODES / 64, 256, 0, stream>>>(out, BTw);
    layer_kernel_direct<<<N_NODES / 32, 512, 0, stream>>>(adj + NN, BTw, out,
                                                          out);
  }
}

// Round 6
// 157.610 us; speedup vs baseline: 3.9000x; 1.0468x over previous
//
#include <hip/hip_runtime.h>
#include <hip/hip_bf16.h>

typedef __bf16 bf16x8 __attribute__((ext_vector_type(8)));
typedef float f32x4 __attribute__((ext_vector_type(4)));
typedef float f32x16 __attribute__((ext_vector_type(16)));
typedef int int4v __attribute__((ext_vector_type(4)));
typedef unsigned int uint4v __attribute__((ext_vector_type(4)));
typedef unsigned short u16x8 __attribute__((ext_vector_type(8)));

#define N_NODES 8192
#define D_FEAT 128

// Round-5 budget (amplification-measured): pack ~115us @4.6TB/s, GEMM 2x22us,
// bpk ~3us. This round: FUSE pack+GEMM into one HBM pass per layer. Block
// owns 32 output rows; per 256-int K-chunk: ballot-pack rows into LDS bits
// (chunk-local layout == global layout: slot s=2e+hi <-> dword 8c+s), then
// verified unpack->mfma_32x32x16 against L2-resident Bpk. Distance-2 A
// prefetch; deg from ballot popcounts in-kernel. Deletes bits HBM round-trip.

// ---------------------------------------------------------------------------
// Bit->bf16 pair unpack: byte (8 adjacency bits) -> bf16x8 of {0.0, 1.0}.
__device__ __forceinline__ bf16x8 unpack_byte(unsigned dword, int sh) {
  unsigned P = ((dword >> sh) & 0xFFu) * 0x8001u;
  uint4v c;
  c[0] = (P & 0x10001u) * 0x3F80u;
  c[1] = ((P >> 2) & 0x10001u) * 0x3F80u;
  c[2] = ((P >> 4) & 0x10001u) * 0x3F80u;
  c[3] = ((P >> 6) & 0x10001u) * 0x3F80u;
  return __builtin_bit_cast(bf16x8, c);
}

// ---------------------------------------------------------------------------
// Bpk fragment build (verified rounds 2-5). Fragment f = kk*256 + ng*64 + l
// holds, at element e: F[sigma(kk*16 + (l>>5)*8 + e)][ng*32 + (l&31)],
// sigma(p) = 256*(p>>8) + 32*((p>>3)&7) + 4*(p&7) + ((p>>6)&3)
__device__ __forceinline__ void bpk32_store(const float* __restrict__ src,
                                            unsigned short* __restrict__ Bpk,
                                            int W) {
  const int kk = W >> 8;
  const int ng = (W >> 6) & 3;
  const int l = W & 63;
  const int d = ng * 32 + (l & 31);
  const int p0 = kk * 16 + (l >> 5) * 8;
  const int n0 = (p0 >> 8) * 256 + ((p0 >> 3) & 7) * 32 + ((p0 >> 6) & 3);
  u16x8 pk;
#pragma unroll
  for (int e = 0; e < 8; ++e) {
    __bf16 v = (__bf16)src[(long)(n0 + 4 * e) * D_FEAT + d];
    pk[e] = __builtin_bit_cast(unsigned short, v);
  }
  *(u16x8*)(Bpk + (long)W * 8) = pk;
}

__global__ __launch_bounds__(256) void bpk_build32_kernel(
    const float* __restrict__ src, unsigned short* __restrict__ Bpk) {
  bpk32_store(src, Bpk, blockIdx.x * 256 + threadIdx.x);
}

// ---------------------------------------------------------------------------
// Fused layer kernel: grid 256 blocks x 512 thr. Block = rows [32*bx,32*bx+32),
// all 128 cols. 8 waves = 4 col-groups (ng=w&3) x 2 K-halves (kh2=w>>2).
// K streamed in 32 chunks of 256 ints/row (32 KiB/chunk/block).
__global__ __launch_bounds__(512, 2) void fused_layer_kernel(
    const int* __restrict__ adj, const unsigned short* __restrict__ Bpk,
    const float* __restrict__ fin, float* __restrict__ fout) {
  __shared__ unsigned bitsL[2][320];              // [buf][row*10 + slot0..7]
  __shared__ int degL[32];
  __shared__ __align__(16) f32x4 red[4][4][64];   // 16 KiB split-K combine

  const int tid = threadIdx.x;
  const int lane = tid & 63;
  const int w = tid >> 6;       // 0..7
  const int ng = w & 3;         // 32-col group
  const int kh2 = w >> 2;       // K-half of each chunk
  const int l31 = lane & 31;
  const int lh = lane >> 5;
  const int lh8 = lh * 8;
  const int m0 = blockIdx.x * 32;

  // A-stream: wave w loads rows {w, 8+w, 16+w, 24+w}; 1 KiB/row/chunk.
  const int4v* aB0 = (const int4v*)(adj + ((long)(m0 + w) << 13)) + lane;
  const int4v* aB1 = (const int4v*)(adj + ((long)(m0 + 8 + w) << 13)) + lane;
  const int4v* aB2 = (const int4v*)(adj + ((long)(m0 + 16 + w) << 13)) + lane;
  const int4v* aB3 = (const int4v*)(adj + ((long)(m0 + 24 + w) << 13)) + lane;

  int cnt0 = 0, cnt1 = 0, cnt2 = 0, cnt3 = 0;

  // Ballot-pack 4 rows (REGS[0..3]) of one chunk into bitsL[BUF].
  // Bit l of slot s=2e+hi of row = adjacency int (chunk*256 + 4l + e) != 0;
  // identical bit layout to the verified global pack (slot s == dword 8c+s).
#define DO_BALLOT(R0, R1, R2, R3, BUF)                                       \
  {                                                                          \
    const int e_ = lane >> 1;                                                \
    _Pragma("unroll") for (int i = 0; i < 4; ++i) {                          \
      int4v vv = (i == 0) ? (R0) : (i == 1) ? (R1) : (i == 2) ? (R2) : (R3); \
      unsigned long long b0 = __ballot(vv[0] != 0);                          \
      unsigned long long b1 = __ballot(vv[1] != 0);                          \
      unsigned long long b2 = __ballot(vv[2] != 0);                          \
      unsigned long long b3 = __ballot(vv[3] != 0);                          \
      int pc = __popcll(b0) + __popcll(b1) + __popcll(b2) + __popcll(b3);    \
      if (i == 0) cnt0 += pc;                                                \
      if (i == 1) cnt1 += pc;                                                \
      if (i == 2) cnt2 += pc;                                                \
      if (i == 3) cnt3 += pc;                                                \
      unsigned long long bsel = b0;                                          \
      if (e_ == 1) bsel = b1;                                                \
      if (e_ == 2) bsel = b2;                                                \
      if (e_ == 3) bsel = b3;                                                \
      unsigned dv = (lane & 1) ? (unsigned)(bsel >> 32) : (unsigned)bsel;    \
      if (lane < 8) bitsL[BUF][(i * 8 + w) * 10 + lane] = dv;                \
    }                                                                        \
  }

  f32x16 acc = {0.f, 0.f, 0.f, 0.f, 0.f, 0.f, 0.f, 0.f,
                0.f, 0.f, 0.f, 0.f, 0.f, 0.f, 0.f, 0.f};

  // GEMM one chunk: 8 kk-steps of this wave's K-half from bitsL[BUF].
  // kk = c*16 + kh2*8 + kkl; q[kkl>>1], sh = (kkl&1)*16 + lh*8 (verified map).
#define DO_GEMM(C, BUF)                                                      \
  {                                                                          \
    const bf16x8* bp = (const bf16x8*)Bpk +                                  \
                       (((long)((C)*16 + kh2 * 8)) << 8) + ng * 64 + lane;   \
    bf16x8 bv0 = bp[0], bv1 = bp[256], bv2 = bp[512], bv3 = bp[768];         \
    bf16x8 bv4 = bp[1024], bv5 = bp[1280], bv6 = bp[1536], bv7 = bp[1792];   \
    const unsigned* bl = &bitsL[BUF][l31 * 10 + kh2 * 4];                    \
    unsigned q0 = bl[0], q1 = bl[1], q2 = bl[2], q3 = bl[3];                 \
    acc = __builtin_amdgcn_mfma_f32_32x32x16_bf16(unpack_byte(q0, lh8),      \
                                                  bv0, acc, 0, 0, 0);        \
    acc = __builtin_amdgcn_mfma_f32_32x32x16_bf16(unpack_byte(q0, lh8 + 16), \
                                                  bv1, acc, 0, 0, 0);        \
    acc = __builtin_amdgcn_mfma_f32_32x32x16_bf16(unpack_byte(q1, lh8),      \
                                                  bv2, acc, 0, 0, 0);        \
    acc = __builtin_amdgcn_mfma_f32_32x32x16_bf16(unpack_byte(q1, lh8 + 16), \
                                                  bv3, acc, 0, 0, 0);        \
    acc = __builtin_amdgcn_mfma_f32_32x32x16_bf16(unpack_byte(q2, lh8),      \
                                                  bv4, acc, 0, 0, 0);        \
    acc = __builtin_amdgcn_mfma_f32_32x32x16_bf16(unpack_byte(q2, lh8 + 16), \
                                                  bv5, acc, 0, 0, 0);        \
    acc = __builtin_amdgcn_mfma_f32_32x32x16_bf16(unpack_byte(q3, lh8),      \
                                                  bv6, acc, 0, 0, 0);        \
    acc = __builtin_amdgcn_mfma_f32_32x32x16_bf16(unpack_byte(q3, lh8 + 16), \
                                                  bv7, acc, 0, 0, 0);        \
  }

  // Prologue: chunk 0 -> avA, chunk 1 -> avB, ballot chunk 0.
  int4v avA0 = aB0[0], avA1 = aB1[0], avA2 = aB2[0], avA3 = aB3[0];
  int4v avB0 = aB0[64], avB1 = aB1[64], avB2 = aB2[64], avB3 = aB3[64];
  DO_BALLOT(avA0, avA1, avA2, avA3, 0)
  __syncthreads();

  // BODY(c): prefetch chunk c+2 into CUR (=buf[c&1], holds already-balloted
  // chunk c); ballot chunk c+1 from OTH (loaded one full iteration ago);
  // GEMM chunk c; barrier.
#define BODY(C, CUR0, CUR1, CUR2, CUR3, OTH0, OTH1, OTH2, OTH3)              \
  {                                                                          \
    if ((C) + 2 < 32) {                                                      \
      CUR0 = aB0[((C) + 2) * 64];                                            \
      CUR1 = aB1[((C) + 2) * 64];                                            \
      CUR2 = aB2[((C) + 2) * 64];                                            \
      CUR3 = aB3[((C) + 2) * 64];                                            \
    }                                                                        \
    if ((C) + 1 < 32) DO_BALLOT(OTH0, OTH1, OTH2, OTH3, ((C) + 1) & 1)       \
    DO_GEMM((C), (C)&1)                                                      \
    __syncthreads();                                                         \
  }

  for (int c = 0; c < 32; c += 2) {
    BODY(c, avA0, avA1, avA2, avA3, avB0, avB1, avB2, avB3)
    BODY(c + 1, avB0, avB1, avB2, avB3, avA0, avA1, avA2, avA3)
  }
#undef BODY
#undef DO_GEMM
#undef DO_BALLOT

  // Degrees (uniform per wave) -> LDS.
  if (lane == 0) {
    degL[w] = cnt0;
    degL[8 + w] = cnt1;
    degL[16 + w] = cnt2;
    degL[24 + w] = cnt3;
  }

  // Split-K2 combine: kh2=1 waves store, kh2=0 waves add.
  if (kh2) {
#define ST4(c)                                                               \
  red[ng][c][lane] = __builtin_shufflevector(acc, acc, 4 * (c), 4 * (c) + 1, \
                                             4 * (c) + 2, 4 * (c) + 3);
    ST4(0) ST4(1) ST4(2) ST4(3)
#undef ST4
  }
  __syncthreads();
  if (kh2) return;
#pragma unroll
  for (int c = 0; c < 4; ++c) {
    f32x4 r = red[ng][c][lane];
#pragma unroll
    for (int k = 0; k < 4; ++k) acc[4 * c + k] += r[k];
  }

  // Epilogue (verified m101 C/D layout): col = ng*32+l31,
  // row32 = (r&3) + 8*(r>>2) + 4*lh.
#pragma unroll
  for (int r = 0; r < 16; ++r) {
    const int row32 = (r & 3) + 8 * (r >> 2) + 4 * lh;
    const int row = m0 + row32;
    const int dg = degL[row32];
    const long off = (long)row * D_FEAT + ng * 32 + l31;
    fout[off] = dg > 0 ? acc[r] * (1.0f / (float)dg) : fin[off];
  }
}

// ---------------------------------------------------------------------------
// Fallback path (round-1 verified), used only if ws too small.
__global__ __launch_bounds__(256) void transpose_cast_kernel(
    const float* __restrict__ src, unsigned short* __restrict__ dst) {
  __shared__ float tile[64][129];
  const int t = threadIdx.x;
  const int nbase = blockIdx.x * 64;
#pragma unroll
  for (int i = 0; i < 32; ++i) {
    int idx = t + i * 256;
    int nl = idx >> 7;
    int d = idx & 127;
    tile[nl][d] = src[(long)(nbase + nl) * D_FEAT + d];
  }
  __syncthreads();
#pragma unroll
  for (int i = 0; i < 32; ++i) {
    int idx = t + i * 256;
    int d = idx >> 6;
    int nl = idx & 63;
    __bf16 b = (__bf16)tile[nl][d];
    dst[(long)d * N_NODES + nbase + nl] = __builtin_bit_cast(unsigned short, b);
  }
}

__global__ __launch_bounds__(512) void layer_kernel_direct(
    const int* __restrict__ adj, const unsigned short* __restrict__ BT,
    const float* __restrict__ fin, float* __restrict__ fout) {
  const int tid = threadIdx.x;
  const int lane = tid & 63;
  const int w = tid >> 6;
  const int m0 = blockIdx.x * 32 + (w >> 2) * 16;
  const int n0 = (w & 3) * 32;
  const int lr = lane & 15;
  const int kc = lane >> 4;

  const int4v* ap = (const int4v*)(adj + (long)(m0 + lr) * N_NODES + kc * 8);
  const bf16x8* bp0 = (const bf16x8*)(BT + (long)(n0 + lr) * N_NODES + kc * 8);
  const bf16x8* bp1 =
      (const bf16x8*)(BT + (long)(n0 + 16 + lr) * N_NODES + kc * 8);

  f32x4 acc0 = {0.f, 0.f, 0.f, 0.f};
  f32x4 acc1 = {0.f, 0.f, 0.f, 0.f};
  int degv = 0;

#pragma unroll 4
  for (int k = 0; k < N_NODES; k += 32) {
    int4v alo = ap[0];
    int4v ahi = ap[1];
    bf16x8 b0 = bp0[0];
    bf16x8 b1 = bp1[0];
    ap += 8;
    bp0 += 4;
    bp1 += 4;
    unsigned short u[8];
    u[0] = alo[0] ? 0x3F80 : 0;
    u[1] = alo[1] ? 0x3F80 : 0;
    u[2] = alo[2] ? 0x3F80 : 0;
    u[3] = alo[3] ? 0x3F80 : 0;
    u[4] = ahi[0] ? 0x3F80 : 0;
    u[5] = ahi[1] ? 0x3F80 : 0;
    u[6] = ahi[2] ? 0x3F80 : 0;
    u[7] = ahi[3] ? 0x3F80 : 0;
    degv += alo[0] + alo[1] + alo[2] + alo[3] + ahi[0] + ahi[1] + ahi[2] +
            ahi[3];
    bf16x8 a;
    memcpy(&a, u, 16);
    acc0 = __builtin_amdgcn_mfma_f32_16x16x32_bf16(a, b0, acc0, 0, 0, 0);
    acc1 = __builtin_amdgcn_mfma_f32_16x16x32_bf16(a, b1, acc1, 0, 0, 0);
  }

  degv += __shfl_xor(degv, 16);
  degv += __shfl_xor(degv, 32);
  int dgv[4];
#pragma unroll
  for (int j = 0; j < 4; ++j) dgv[j] = __shfl(degv, kc * 4 + j);

#pragma unroll
  for (int t = 0; t < 2; ++t) {
    const f32x4 acc = t ? acc1 : acc0;
    const int col = n0 + t * 16 + lr;
#pragma unroll
    for (int j = 0; j < 4; ++j) {
      const long off = (long)(m0 + kc * 4 + j) * D_FEAT + col;
      fout[off] = dgv[j] > 0 ? acc[j] * (1.0f / (float)dgv[j]) : fin[off];
    }
  }
}

// ---------------------------------------------------------------------------
extern "C" void kernel_launch(void* const* d_in, const int* in_sizes, int n_in,
                              void* d_out, int out_size, void* d_ws,
                              size_t ws_size, hipStream_t stream) {
  const float* features = (const float*)d_in[0];
  const int* adj = (const int*)d_in[1];
  float* out = (float*)d_out;
  const long NN = (long)N_NODES * N_NODES;

  const size_t BPK_BYTES = (size_t)D_FEAT * N_NODES * 2;  // 2 MiB
  const size_t NEED = BPK_BYTES + 256;

  if (ws_size >= NEED) {
    unsigned short* Bpk = (unsigned short*)d_ws;

    // K0: layer-1 Bpk from input features (~2 us).
    bpk_build32_kernel<<<512, 256, 0, stream>>>(features, Bpk);
    // K1: fused pack+GEMM layer 1 (streams adj1 256 MiB once).
    fused_layer_kernel<<<256, 512, 0, stream>>>(adj, Bpk, features, out);
    // K2: rebuild Bpk from layer-1 output.
    bpk_build32_kernel<<<512, 256, 0, stream>>>(out, Bpk);
    // K3: fused pack+GEMM layer 2 (streams adj2 256 MiB once).
    fused_layer_kernel<<<256, 512, 0, stream>>>(adj + NN, Bpk, out, out);
  } else {
    // Fallback: round-1 verified path (needs only 2 MiB ws)
    unsigned short* BTw = (unsigned short*)d_ws;
    transpose_cast_kernel<<<N_NODES / 64, 256, 0, stream>>>(features, BTw);
    layer_kernel_direct<<<N_NODES / 32, 512, 0, stream>>>(adj, BTw, features,
                                                          out);
    transpose_cast_kernel<<<N_NODES / 64, 256, 0, stream>>>(out, BTw);
    layer_kernel_direct<<<N_NODES / 32, 512, 0, stream>>>(adj + NN, BTw, out,
                                                          out);
  }
}